// Round 5
// baseline (54552.197 us; speedup 1.0000x reference)
//
#include <hip/hip_runtime.h>
#include <cstdint>

#define BB 32
#define TT 1024
#define II 512
#define HH 1024
#define KK 1536   // II + HH
#define NTHREADS 512
#define NBLOCKS  256

// async 16B global->LDS (lane-linear dest: wave-uniform base + lane*16)
__device__ __forceinline__ void gload16(const void* g, void* l) {
  __builtin_amdgcn_global_load_lds(
      (const __attribute__((address_space(1))) unsigned int*)g,
      (__attribute__((address_space(3))) unsigned int*)l, 16, 0, 0);
}

// generation barrier, agent scope. cnt=bar[0], gen=bar[1].
__device__ __forceinline__ void grid_barrier(unsigned* bar) {
  __syncthreads();
  if (threadIdx.x == 0) {
    __threadfence();  // publish this block's out[] writes device-wide
    unsigned g = __hip_atomic_load(bar + 1, __ATOMIC_RELAXED, __HIP_MEMORY_SCOPE_AGENT);
    unsigned old = __hip_atomic_fetch_add(bar, 1u, __ATOMIC_ACQ_REL, __HIP_MEMORY_SCOPE_AGENT);
    if (old == NBLOCKS - 1) {
      __hip_atomic_store(bar, 0u, __ATOMIC_RELAXED, __HIP_MEMORY_SCOPE_AGENT);
      __hip_atomic_fetch_add(bar + 1, 1u, __ATOMIC_RELEASE, __HIP_MEMORY_SCOPE_AGENT);
    } else {
      while (__hip_atomic_load(bar + 1, __ATOMIC_ACQUIRE, __HIP_MEMORY_SCOPE_AGENT) == g)
        __builtin_amdgcn_s_sleep(1);
    }
    __threadfence();  // invalidate caches before reading other blocks' h
  }
  __syncthreads();
}

// Persistent LSTM. Block owns 4 units; wave w: unit = bid*4 + (w>>1),
// batches (w&1)*16..+15. Slot i of lane l accumulates output o = l^i
// (o>>2 = local batch, o&3 = gate) -> 63-shuffle transpose-reduce.
__global__ __launch_bounds__(NTHREADS, 2)
void lstm_persist(const float* __restrict__ x, const float* __restrict__ W,
                  const float* __restrict__ bias, float* __restrict__ out,
                  unsigned* __restrict__ bar)
{
  __shared__ __align__(16) float smA[BB * II];  // 64KB: x_t, then h cols 512..1023
  __shared__ __align__(16) float smB[BB * II];  // 64KB: h cols 0..511

  const int tid   = threadIdx.x;
  const int lane  = tid & 63;
  const int wave  = tid >> 6;
  const int u     = blockIdx.x * 4 + (wave >> 1);
  const int bbase = (wave & 1) * 16;
  const int g4    = lane >> 2;   // lane group 0..15
  const int q     = lane & 3;    // this lane's final gate (0:i 1:f 2:g 3:o)

  // ---- prologue: W rows, gate-permuted per lane (wr[r] holds gate q^r) ----
  float wr[4][24];
  #pragma unroll
  for (int r = 0; r < 4; ++r) {
    const int qq = q ^ r;
    const float* row = W + (size_t)(qq * HH + u) * KK;
    #pragma unroll
    for (int j = 0; j < 2; ++j) {            // x cols: k = 4*lane + 256*j
      float4 v = *(const float4*)(row + 4 * lane + 256 * j);
      wr[r][4*j+0] = v.x; wr[r][4*j+1] = v.y; wr[r][4*j+2] = v.z; wr[r][4*j+3] = v.w;
    }
    #pragma unroll
    for (int j = 0; j < 4; ++j) {            // h cols: k = 512 + 4*lane + 256*j
      float4 v = *(const float4*)(row + 512 + 4 * lane + 256 * j);
      wr[r][8+4*j+0] = v.x; wr[r][8+4*j+1] = v.y; wr[r][8+4*j+2] = v.z; wr[r][8+4*j+3] = v.w;
    }
  }
  const float bmine = bias[q * HH + u];
  float c_reg = 0.0f;

  // stage x_0 -> A
  #pragma unroll
  for (int it = 0; it < 8; ++it) {
    int idx = it * NTHREADS + tid;           // 0..4095 float4s
    int b = idx >> 7, c4 = idx & 127;
    gload16(x + (size_t)b * TT * II + 4 * c4, smA + 4 * idx);
  }
  __syncthreads();

  float acc[64];

  #pragma unroll 1
  for (int t = 0; t < TT; ++t) {
    #pragma unroll
    for (int i = 0; i < 64; ++i) acc[i] = 0.0f;

    if (t > 0) {
      grid_barrier(bar);
      // issue h cols 0..511 -> B  (x_t already in A from prefetch)
      #pragma unroll
      for (int it = 0; it < 8; ++it) {
        int idx = it * NTHREADS + tid;
        int b = idx >> 7, c4 = idx & 127;
        gload16(out + (size_t)b * TT * HH + (size_t)(t - 1) * HH + 4 * c4, smB + 4 * idx);
      }
    }

    // ---- x-part from A (overlaps h-lower staging) ----
    #pragma unroll
    for (int m = 0; m < 16; ++m) {
      const int bl = bbase + (g4 ^ m);
      const float4* Ar = (const float4*)(smA + bl * II);
      float4 a0 = Ar[lane], a1 = Ar[lane + 64];
      #pragma unroll
      for (int r = 0; r < 4; ++r) {
        float s = acc[4*m+r];
        s = fmaf(a0.x, wr[r][0], s); s = fmaf(a0.y, wr[r][1], s);
        s = fmaf(a0.z, wr[r][2], s); s = fmaf(a0.w, wr[r][3], s);
        s = fmaf(a1.x, wr[r][4], s); s = fmaf(a1.y, wr[r][5], s);
        s = fmaf(a1.z, wr[r][6], s); s = fmaf(a1.w, wr[r][7], s);
        acc[4*m+r] = s;
      }
    }

    if (t > 0) {
      __syncthreads();   // h-lower staged (vmcnt drain); all waves done reading A
      // issue h cols 512..1023 -> A (overlaps h-lower compute)
      #pragma unroll
      for (int it = 0; it < 8; ++it) {
        int idx = it * NTHREADS + tid;
        int b = idx >> 7, c4 = idx & 127;
        gload16(out + (size_t)b * TT * HH + (size_t)(t - 1) * HH + 512 + 4 * c4, smA + 4 * idx);
      }

      // ---- h cols 0..511 from B ----
      #pragma unroll
      for (int m = 0; m < 16; ++m) {
        const int bl = bbase + (g4 ^ m);
        const float4* Br = (const float4*)(smB + bl * II);
        float4 h0 = Br[lane], h1 = Br[lane + 64];
        #pragma unroll
        for (int r = 0; r < 4; ++r) {
          float s = acc[4*m+r];
          s = fmaf(h0.x, wr[r][ 8], s); s = fmaf(h0.y, wr[r][ 9], s);
          s = fmaf(h0.z, wr[r][10], s); s = fmaf(h0.w, wr[r][11], s);
          s = fmaf(h1.x, wr[r][12], s); s = fmaf(h1.y, wr[r][13], s);
          s = fmaf(h1.z, wr[r][14], s); s = fmaf(h1.w, wr[r][15], s);
          acc[4*m+r] = s;
        }
      }

      __syncthreads();   // h-upper staged
      // ---- h cols 512..1023 from A ----
      #pragma unroll
      for (int m = 0; m < 16; ++m) {
        const int bl = bbase + (g4 ^ m);
        const float4* Ar = (const float4*)(smA + bl * II);
        float4 h2 = Ar[lane], h3 = Ar[lane + 64];
        #pragma unroll
        for (int r = 0; r < 4; ++r) {
          float s = acc[4*m+r];
          s = fmaf(h2.x, wr[r][16], s); s = fmaf(h2.y, wr[r][17], s);
          s = fmaf(h2.z, wr[r][18], s); s = fmaf(h2.w, wr[r][19], s);
          s = fmaf(h3.x, wr[r][20], s); s = fmaf(h3.y, wr[r][21], s);
          s = fmaf(h3.z, wr[r][22], s); s = fmaf(h3.w, wr[r][23], s);
          acc[4*m+r] = s;
        }
      }
    }

    // ---- transpose-reduce: lane l ends with full sum for output o = l ----
    #pragma unroll
    for (int half = 32; half >= 1; half >>= 1) {
      #pragma unroll
      for (int i = 0; i < half; ++i)
        acc[i] += __shfl_xor(acc[i + half], half, 64);
    }

    // ---- epilogue: q=0:i 1:f 2:g 3:o ; c lives on q==1 lanes ----
    {
      float gv = acc[0] + bmine;
      float y  = (q == 2) ? 2.0f * gv : gv;
      float sg = 1.0f / (1.0f + __expf(-y));
      float act = (q == 2) ? 2.0f * sg - 1.0f : sg;   // tanh via 2*sigma(2x)-1
      float r2 = __shfl_xor(act, 2, 64);              // q0 gets g; q1 gets o
      float p  = (q == 1) ? act * c_reg : act * r2;   // q0: i*g ; q1: f*c
      float r1 = __shfl_xor(p, 1, 64);                // q1 gets i*g
      float cn = p + r1;                              // q1: f*c + i*g
      float so = 1.0f / (1.0f + __expf(-2.0f * cn));
      float hv = r2 * (2.0f * so - 1.0f);             // o * tanh(c_new)
      if (q == 1) {
        c_reg = cn;
        out[(size_t)(bbase + g4) * (TT * HH) + (size_t)t * HH + u] = hv;
      }
    }

    // prefetch x_{t+1} -> A ; latency hides under epilogue + barrier
    if (t + 1 < TT) {
      __syncthreads();  // everyone done reading A
      #pragma unroll
      for (int it = 0; it < 8; ++it) {
        int idx = it * NTHREADS + tid;
        int b = idx >> 7, c4 = idx & 127;
        gload16(x + (size_t)b * TT * II + (size_t)(t + 1) * II + 4 * c4, smA + 4 * idx);
      }
    }
  }
}

extern "C" void kernel_launch(void* const* d_in, const int* in_sizes, int n_in,
                              void* d_out, int out_size, void* d_ws, size_t ws_size,
                              hipStream_t stream)
{
  const float* x = (const float*)d_in[0];
  const float* W = (const float*)d_in[1];
  const float* b = (const float*)d_in[2];
  float* out = (float*)d_out;
  unsigned* bar = (unsigned*)d_ws;

  hipMemsetAsync(d_ws, 0, 2 * sizeof(unsigned), stream);

  void* args[] = { (void*)&x, (void*)&W, (void*)&b, (void*)&out, (void*)&bar };
  hipLaunchCooperativeKernel((const void*)lstm_persist,
                             dim3(NBLOCKS), dim3(NTHREADS), args, 0, stream);
}

// Round 7
// 30143.585 us; speedup vs baseline: 1.8097x; 1.8097x over previous
//
#include <hip/hip_runtime.h>
#include <cstdint>

#define BB 32
#define TT 1024
#define II 512
#define HH 1024
#define KK 1536   // II + HH
#define NTHREADS 512
#define NBLOCKS  256
#define NCNT 8    // split arrival counters, 128B apart

// async 16B global->LDS (lane-linear dest: wave-uniform base + lane*16)
__device__ __forceinline__ void gload16(const void* g, void* l) {
  __builtin_amdgcn_global_load_lds(
      (const __attribute__((address_space(1))) unsigned int*)g,
      (__attribute__((address_space(3))) unsigned int*)l, 16, 0, 0);
}

// Persistent LSTM. Block owns 4 units; wave w: unit = bid*4 + (w>>1),
// batches (w&1)*16..+15. Slot i of lane l accumulates output o = l^i
// (o>>2 = local batch, o&3 = gate) -> 63-shuffle transpose-reduce.
// Barrier: 8 split counters (relaxed RMW) + master-published generation;
// one release fence before arrival, one acquire fence after observation.
__global__ __launch_bounds__(NTHREADS, 1)
void lstm_persist(const float* __restrict__ x, const float* __restrict__ W,
                  const float* __restrict__ bias, float* __restrict__ out,
                  unsigned* __restrict__ bar)
{
  __shared__ __align__(16) float smA[BB * II];  // 64KB: x_t, then h cols 512..1023
  __shared__ __align__(16) float smB[BB * II];  // 64KB: h cols 0..511

  const int tid   = threadIdx.x;
  const int lane  = tid & 63;
  const int wave  = tid >> 6;
  const int u     = blockIdx.x * 4 + (wave >> 1);
  const int bbase = (wave & 1) * 16;
  const int g4    = lane >> 2;   // lane group 0..15
  const int q     = lane & 3;    // this lane's final gate (0:i 1:f 2:g 3:o)

  // ---- prologue: W rows, gate-permuted per lane (wr[r] holds gate q^r) ----
  float wr[4][24];
  #pragma unroll
  for (int r = 0; r < 4; ++r) {
    const int qq = q ^ r;
    const float* row = W + (size_t)(qq * HH + u) * KK;
    #pragma unroll
    for (int j = 0; j < 2; ++j) {            // x cols: k = 4*lane + 256*j
      float4 v = *(const float4*)(row + 4 * lane + 256 * j);
      wr[r][4*j+0] = v.x; wr[r][4*j+1] = v.y; wr[r][4*j+2] = v.z; wr[r][4*j+3] = v.w;
    }
    #pragma unroll
    for (int j = 0; j < 4; ++j) {            // h cols: k = 512 + 4*lane + 256*j
      float4 v = *(const float4*)(row + 512 + 4 * lane + 256 * j);
      wr[r][8+4*j+0] = v.x; wr[r][8+4*j+1] = v.y; wr[r][8+4*j+2] = v.z; wr[r][8+4*j+3] = v.w;
    }
  }
  const float bmine = bias[q * HH + u];
  float c_reg = 0.0f;

  // stage x_0 -> A (drained by the vmcnt(0) the compiler emits at loop-top syncthreads)
  #pragma unroll
  for (int it = 0; it < 8; ++it) {
    int idx = it * NTHREADS + tid;           // 0..4095 float4s
    int b = idx >> 7, c4 = idx & 127;
    gload16(x + (size_t)b * TT * II + 4 * c4, smA + 4 * idx);
  }

  float acc[64];

  #pragma unroll 1
  for (int t = 0; t < TT; ++t) {
    __syncthreads();   // A (x_t) staged; epilogue/prefetch of prev iter ordered

    #pragma unroll
    for (int i = 0; i < 64; ++i) acc[i] = 0.0f;

    // ---- x-part from A — no dependence on h(t-1); hides barrier wait ----
    #pragma unroll
    for (int m = 0; m < 16; ++m) {
      const int bl = bbase + (g4 ^ m);
      const float4* Ar = (const float4*)(smA + bl * II);
      float4 a0 = Ar[lane], a1 = Ar[lane + 64];
      #pragma unroll
      for (int r = 0; r < 4; ++r) {
        float s = acc[4*m+r];
        s = fmaf(a0.x, wr[r][0], s); s = fmaf(a0.y, wr[r][1], s);
        s = fmaf(a0.z, wr[r][2], s); s = fmaf(a0.w, wr[r][3], s);
        s = fmaf(a1.x, wr[r][4], s); s = fmaf(a1.y, wr[r][5], s);
        s = fmaf(a1.z, wr[r][6], s); s = fmaf(a1.w, wr[r][7], s);
        acc[4*m+r] = s;
      }
    }

    if (t > 0) {
      // ---- wait for generation t (h(t-1) globally visible) ----
      if (tid == 0) {
        if (blockIdx.x == 0) {
          const unsigned target = (unsigned)NBLOCKS * (unsigned)t;
          unsigned sum;
          do {
            sum = 0;
            #pragma unroll
            for (int k = 0; k < NCNT; ++k)
              sum += __hip_atomic_load(bar + 32 + 32 * k, __ATOMIC_RELAXED,
                                       __HIP_MEMORY_SCOPE_AGENT);
          } while (sum < target);
          asm volatile("" ::: "memory");
          __hip_atomic_store(bar, (unsigned)t, __ATOMIC_RELAXED,
                             __HIP_MEMORY_SCOPE_AGENT);
        } else {
          while (__hip_atomic_load(bar, __ATOMIC_RELAXED,
                                   __HIP_MEMORY_SCOPE_AGENT) < (unsigned)t)
            __builtin_amdgcn_s_sleep(1);
        }
        __builtin_amdgcn_fence(__ATOMIC_ACQUIRE, "agent");  // one inv per block per step
      }
      __syncthreads();

      // issue h cols 0..511 -> B
      #pragma unroll
      for (int it = 0; it < 8; ++it) {
        int idx = it * NTHREADS + tid;
        int b = idx >> 7, c4 = idx & 127;
        gload16(out + (size_t)b * TT * HH + (size_t)(t - 1) * HH + 4 * c4, smB + 4 * idx);
      }
      __syncthreads();   // B staged (auto vmcnt drain); all waves done reading A

      // issue h cols 512..1023 -> A (overlaps h-lower compute)
      #pragma unroll
      for (int it = 0; it < 8; ++it) {
        int idx = it * NTHREADS + tid;
        int b = idx >> 7, c4 = idx & 127;
        gload16(out + (size_t)b * TT * HH + (size_t)(t - 1) * HH + 512 + 4 * c4, smA + 4 * idx);
      }

      // ---- h cols 0..511 from B ----
      #pragma unroll
      for (int m = 0; m < 16; ++m) {
        const int bl = bbase + (g4 ^ m);
        const float4* Br = (const float4*)(smB + bl * II);
        float4 h0 = Br[lane], h1 = Br[lane + 64];
        #pragma unroll
        for (int r = 0; r < 4; ++r) {
          float s = acc[4*m+r];
          s = fmaf(h0.x, wr[r][ 8], s); s = fmaf(h0.y, wr[r][ 9], s);
          s = fmaf(h0.z, wr[r][10], s); s = fmaf(h0.w, wr[r][11], s);
          s = fmaf(h1.x, wr[r][12], s); s = fmaf(h1.y, wr[r][13], s);
          s = fmaf(h1.z, wr[r][14], s); s = fmaf(h1.w, wr[r][15], s);
          acc[4*m+r] = s;
        }
      }

      __syncthreads();   // h-upper staged
      // ---- h cols 512..1023 from A ----
      #pragma unroll
      for (int m = 0; m < 16; ++m) {
        const int bl = bbase + (g4 ^ m);
        const float4* Ar = (const float4*)(smA + bl * II);
        float4 h2 = Ar[lane], h3 = Ar[lane + 64];
        #pragma unroll
        for (int r = 0; r < 4; ++r) {
          float s = acc[4*m+r];
          s = fmaf(h2.x, wr[r][16], s); s = fmaf(h2.y, wr[r][17], s);
          s = fmaf(h2.z, wr[r][18], s); s = fmaf(h2.w, wr[r][19], s);
          s = fmaf(h3.x, wr[r][20], s); s = fmaf(h3.y, wr[r][21], s);
          s = fmaf(h3.z, wr[r][22], s); s = fmaf(h3.w, wr[r][23], s);
          acc[4*m+r] = s;
        }
      }
    }

    // ---- transpose-reduce: lane l ends with full sum for output o = l ----
    #pragma unroll
    for (int half = 32; half >= 1; half >>= 1) {
      #pragma unroll
      for (int i = 0; i < half; ++i)
        acc[i] += __shfl_xor(acc[i + half], half, 64);
    }

    // ---- epilogue: q=0:i 1:f 2:g 3:o ; c lives on q==1 lanes ----
    {
      float gv = acc[0] + bmine;
      float y  = (q == 2) ? 2.0f * gv : gv;
      float sg = 1.0f / (1.0f + __expf(-y));
      float act = (q == 2) ? 2.0f * sg - 1.0f : sg;   // tanh via 2*sigma(2x)-1
      float r2 = __shfl_xor(act, 2, 64);              // q0 gets g; q1 gets o
      float p  = (q == 1) ? act * c_reg : act * r2;   // q0: i*g ; q1: f*c
      float r1 = __shfl_xor(p, 1, 64);                // q1 gets i*g
      float cn = p + r1;                              // q1: f*c + i*g
      float so = 1.0f / (1.0f + __expf(-2.0f * cn));
      float hv = r2 * (2.0f * so - 1.0f);             // o * tanh(c_new)
      if (q == 1) {
        c_reg = cn;
        out[(size_t)(bbase + g4) * (TT * HH) + (size_t)t * HH + u] = hv;
      }
    }

    if (t + 1 < TT) {
      // each wave drains its own h-store so tid0's release fence covers all of them
      asm volatile("s_waitcnt vmcnt(0)" ::: "memory");
      __syncthreads();   // all waves' stores in L2; everyone done reading A

      // arrive (release) BEFORE issuing the x-prefetch so the fence's internal
      // waitcnt doesn't stall on the prefetch
      if (tid == 0) {
        __builtin_amdgcn_fence(__ATOMIC_RELEASE, "agent");  // wbl2: flush h stores
        __hip_atomic_fetch_add(bar + 32 + 32 * (blockIdx.x & (NCNT - 1)), 1u,
                               __ATOMIC_RELAXED, __HIP_MEMORY_SCOPE_AGENT);
      }

      // prefetch x_{t+1} -> A ; completes under next iter's top syncthreads
      #pragma unroll
      for (int it = 0; it < 8; ++it) {
        int idx = it * NTHREADS + tid;
        int b = idx >> 7, c4 = idx & 127;
        gload16(x + (size_t)b * TT * II + (size_t)(t + 1) * II + 4 * c4, smA + 4 * idx);
      }
    }
  }
}

extern "C" void kernel_launch(void* const* d_in, const int* in_sizes, int n_in,
                              void* d_out, int out_size, void* d_ws, size_t ws_size,
                              hipStream_t stream)
{
  const float* x = (const float*)d_in[0];
  const float* W = (const float*)d_in[1];
  const float* b = (const float*)d_in[2];
  float* out = (float*)d_out;
  unsigned* bar = (unsigned*)d_ws;

  // bar[0]=generation, bar[32+32k]=arrival counter k (128B apart)
  hipMemsetAsync(d_ws, 0, 4096, stream);

  void* args[] = { (void*)&x, (void*)&W, (void*)&b, (void*)&out, (void*)&bar };
  hipLaunchCooperativeKernel((const void*)lstm_persist,
                             dim3(NBLOCKS), dim3(NTHREADS), args, 0, stream);
}